// Round 13
// baseline (3852.822 us; speedup 1.0000x reference)
//
#include <hip/hip_runtime.h>

// LSTM w/ hard-sigmoid gates. T=512, B=64, I=H=512.
// R13: full-K h-waves + gx-precompute ring. The LDS partial exchange, both
// barriers, and the third-party update are GONE -- each h-wave owns its 8
// columns end-to-end (consume -> MFMA -> update -> publish in-wave).
//  - h-wave u (wv 4..7): 2 gate-interleaved MFMA tiles (row = 4*j_local+gate,
//    R3-proven) over FULL K=512 -> acc_p[r] = gate r of (batch=B0+l15,
//    j = J0+8u+4p+hi). Lane-local cell update, 2 bf16 publishes.
//  - x-wave u (wv 0..3): gx(t) = x[t]@w_ih + bias for the same 8 columns,
//    into a 4-deep LDS ring; runs <=4 steps ahead (back-pressure: own-WG
//    h-flag >= t-2, single word). R10-proven release/acquire handshake.
//  - Cross-WG: R6-proven per-wave flags (publish -> own vmcnt(0) -> flag),
//    consumers poll all 64 replica flags with one coalesced load (R11-proven).
// Geometry: 4 replicas x 16 batches x 16 WGs (B-frag cols all real).
// R12 lesson: never bundle multiple sync edits; this round composes only
// individually-proven legs and REMOVES legs (no barrier, no HP/XS buffers).
//
// Workspace: [0,4096)    : flags, 4 reps x 64 u32 ([wg][hwave]) -- memset 0
//            [4096,+128K): h double buffer [2][64][512] bf16

#define T_LEN 512
#define BATCH 64
#define ISZ   512
#define HSZ   512

#define NREP 4
#define WPR  16
#define BR   16
#define JW   32
#define NWG  (NREP * WPR)
#define NTHR 512

typedef __bf16 bf16x8 __attribute__((ext_vector_type(8)));
typedef float  f32x4  __attribute__((ext_vector_type(4)));
typedef float  f32x8  __attribute__((ext_vector_type(8)));
typedef int    i32x4  __attribute__((ext_vector_type(4)));

__device__ __forceinline__ bf16x8 cvt8(f32x4 a, f32x4 b) {
  f32x8 t;
  t[0]=a[0]; t[1]=a[1]; t[2]=a[2]; t[3]=a[3];
  t[4]=b[0]; t[5]=b[1]; t[6]=b[2]; t[7]=b[3];
  return __builtin_convertvector(t, bf16x8);   // v_cvt_pk_bf16_f32 pairs
}

__device__ __forceinline__ float fast_tanh(float v) {
  float e = __expf(2.0f * v);
  return 1.0f - 2.0f / (e + 1.0f);   // exact limits at +-inf
}

__device__ __forceinline__ float hsig(float v) {
  return fminf(fmaxf(0.2f * v + 0.5f, 0.0f), 1.0f);
}

__device__ __forceinline__ unsigned bf16bits(float v) {
  union { __bf16 h; unsigned short s; } p;
  p.h = (__bf16)v;
  return (unsigned)p.s;
}

// h loads: sc0 sc1 = bypass L1/L2, served at the device-coherent point
#define HLOAD(i, o)                                                        \
  asm volatile("global_load_dwordx4 %0, %1, off offset:" #o " sc0 sc1"     \
               : "=v"(hfrag[i]) : "v"(hr));
// x loads: plain cached; asm-pinned issue order
#define XLOAD(i, o)                                                        \
  asm volatile("global_load_dwordx4 %0, %1, off offset:" #o                \
               : "=v"(xpre[i]) : "v"(xb));
// 2-byte publish, device-coherent
#define STBF16(p, v)                                                       \
  asm volatile("global_store_short %0, %1, off sc0 sc1"                    \
               :: "v"(p), "v"(v) : "memory");

__global__ __launch_bounds__(NTHR, 2) void lstm_kernel(
    const float* __restrict__ x,      // [T][B][I]
    const float* __restrict__ h0,     // [B][H]
    const float* __restrict__ c0,     // [B][H]
    const float* __restrict__ w_ih,   // [4H][I]
    const float* __restrict__ w_hh,   // [4H][H]
    const float* __restrict__ b_ih,   // [4H]
    const float* __restrict__ b_hh,   // [4H]
    float* __restrict__ out,          // [T][B][H] ++ hn[B][H] ++ cn[B][H]
    unsigned* __restrict__ flags,     // [NREP][16 wg][4 hwave] monotonic
    __bf16* __restrict__ hbuf)        // [2][B][H]
{
  const int bid = blockIdx.x;
  const int rep = bid >> 4;           // 0..3
  const int wgi = bid & 15;           // 0..15
  const int B0  = rep * BR;
  const int J0  = wgi * JW;

  const int tid  = threadIdx.x;
  const int lane = tid & 63;
  const int wv   = tid >> 6;          // 0..7
  const int l15  = lane & 15;         // batch col of A/B/C frags
  const int hi   = lane >> 4;         // 0..3
  const bool xw  = (wv < 4);          // x-waves 0-3 (gx producers), h-waves 4-7
  const int  u   = wv & 3;            // j-block index 0..3
  const int  jb  = J0 + 8 * u;        // this role-pair's 8-column block

  unsigned* myf = flags + rep * 64;   // [wg][hwave]

  // ---- weights: 2 tiles x 16 k-steps, gate-interleaved rows
  //      (row m: gate = m&3, j = jb + 4p + (m>>2)) ----
  bf16x8 wfrag[32];                   // [p][ks]
  {
    const float* W = xw ? w_ih : w_hh;
#pragma unroll
    for (int p = 0; p < 2; ++p) {
      const int grow = (l15 & 3) * HSZ + jb + 4 * p + (l15 >> 2);
      const float* wp = W + (size_t)grow * 512 + hi * 8;
#pragma unroll
      for (int ks = 0; ks < 16; ++ks) {
        f32x4 a = *(const f32x4*)(wp + ks * 32);
        f32x4 b = *(const f32x4*)(wp + ks * 32 + 4);
        wfrag[p * 16 + ks] = cvt8(a, b);
      }
    }
  }

  // ---- lane-local output coords (C/D: col=l15, row=hi*4+r -> gate=r) ----
  const int j0 = jb + hi;             // p=0 column
  const int j1 = jb + 4 + hi;         // p=1 column
  const size_t brow = (size_t)(B0 + l15) * HSZ;

  f32x4 bias0, bias1;                 // x-waves fold bias into gx
  float cst0 = 0.0f, cst1 = 0.0f;     // h-waves carry cell state
  if (xw) {
#pragma unroll
    for (int r = 0; r < 4; ++r) {
      bias0[r] = b_ih[r * HSZ + j0] + b_hh[r * HSZ + j0];
      bias1[r] = b_ih[r * HSZ + j1] + b_hh[r * HSZ + j1];
    }
  } else {
    cst0 = c0[brow + j0];
    cst1 = c0[brow + j1];
  }

  // gx ring: 4 slots x [16 batch][33 j-slots padded] f32x4 (2-way banks max)
  __shared__ __align__(16) f32x4 gx[4][16][33];
  __shared__ unsigned xflag[4];       // x-wave u -> h-wave u, monotonic t+1
  if (tid < 4) xflag[tid] = 0;

  // ---- h0 publish (h-waves, own columns), own drain, own flag = 1 ----
  if (!xw) {
    unsigned s0 = bf16bits(h0[brow + j0]);
    unsigned s1 = bf16bits(h0[brow + j1]);
    const __bf16* hq0 = hbuf + brow + j0;
    const __bf16* hq1 = hbuf + brow + j1;
    STBF16(hq0, s0)
    STBF16(hq1, s1)
    asm volatile("s_waitcnt vmcnt(0)" ::: "memory");
    if (lane == 0)
      __hip_atomic_store(&myf[wgi * 4 + u], 1u,
                         __ATOMIC_RELAXED, __HIP_MEMORY_SCOPE_AGENT);
  }
  __syncthreads();                    // one-time: xflag init visible

  for (int t = 0; t < T_LEN; ++t) {
    if (xw) {
      // ---------- x-wave: produce gx(t), <=4 steps ahead ----------
      // ring slot t&3 free once h-wave u consumed gx(t-4): its flag >= t-2
      // (flag v  <=>  published h_{v-1}  <=>  finished step v-2 incl. gx read)
      if (t >= 4) {
        const unsigned tgt = (unsigned)(t - 2);
        long g = 0;
        while (__hip_atomic_load(&myf[wgi * 4 + u], __ATOMIC_RELAXED,
                                 __HIP_MEMORY_SCOPE_AGENT) < tgt) {
          __builtin_amdgcn_s_sleep(2);
          if (++g > (1L << 20)) break;   // safety: corrupt visibly
        }
      }
      f32x4 acc0 = bias0, acc1 = bias1;
      const float* xr = x + ((size_t)t * BATCH + B0 + l15) * ISZ + hi * 8;
#pragma unroll
      for (int r4 = 0; r4 < 4; ++r4) {   // 4 rounds x 4 k-steps
        const float* xb = xr + r4 * 128;
        f32x4 xpre[8];
        XLOAD(0, 0)   XLOAD(1, 16)  XLOAD(2, 128) XLOAD(3, 144)
        XLOAD(4, 256) XLOAD(5, 272) XLOAD(6, 384) XLOAD(7, 400)
        asm volatile("s_waitcnt vmcnt(0)" ::: "memory");
        __builtin_amdgcn_sched_barrier(0);             // rule #18
        bf16x8 bx[4];
#pragma unroll
        for (int k2 = 0; k2 < 4; ++k2) bx[k2] = cvt8(xpre[2 * k2], xpre[2 * k2 + 1]);
#pragma unroll
        for (int k2 = 0; k2 < 4; ++k2) {
          acc0 = __builtin_amdgcn_mfma_f32_16x16x32_bf16(
              wfrag[r4 * 4 + k2], bx[k2], acc0, 0, 0, 0);
          acc1 = __builtin_amdgcn_mfma_f32_16x16x32_bf16(
              wfrag[16 + r4 * 4 + k2], bx[k2], acc1, 0, 0, 0);
        }
      }
      // deposit gx(t): lds drain, RELEASE flag (R10-proven handshake)
      gx[t & 3][l15][8 * u + hi]     = acc0;
      gx[t & 3][l15][8 * u + 4 + hi] = acc1;
      asm volatile("s_waitcnt lgkmcnt(0)" ::: "memory");
      if (lane == 0)
        __hip_atomic_store(&xflag[u], (unsigned)(t + 1),
                           __ATOMIC_RELEASE, __HIP_MEMORY_SCOPE_WORKGROUP);
    } else {
      // ---------- h-wave: consume -> MFMA -> update -> publish, in-wave ----
      // 1. poll: all 64 h-wave flags of the replica >= t+1 (one coalesced ld)
      {
        const unsigned tgt = (unsigned)(t + 1);
        long g = 0;
        for (;;) {
          unsigned v = __hip_atomic_load(&myf[lane], __ATOMIC_RELAXED,
                                         __HIP_MEMORY_SCOPE_AGENT);
          if (__all((int)(v >= tgt))) break;
          __builtin_amdgcn_s_sleep(1);
          if (++g > (1L << 20)) break;   // safety: corrupt visibly
        }
      }
      __builtin_amdgcn_sched_barrier(0);

      // 2. h_t full-K load: 16 x dwordx4 (16KB/wave, L3-resident buffer)
      const __bf16* hr = hbuf + (size_t)(t & 1) * BATCH * HSZ + brow + hi * 8;
      i32x4 hfrag[16];
      HLOAD(0, 0)    HLOAD(1, 64)   HLOAD(2, 128)  HLOAD(3, 192)
      HLOAD(4, 256)  HLOAD(5, 320)  HLOAD(6, 384)  HLOAD(7, 448)
      HLOAD(8, 512)  HLOAD(9, 576)  HLOAD(10, 640) HLOAD(11, 704)
      HLOAD(12, 768) HLOAD(13, 832) HLOAD(14, 896) HLOAD(15, 960)
      asm volatile("s_waitcnt vmcnt(0)" ::: "memory");
      __builtin_amdgcn_sched_barrier(0);               // rule #18

      // 3. 32 MFMAs (two independent acc chains)
      f32x4 acc0 = (f32x4)(0.0f), acc1 = (f32x4)(0.0f);
#pragma unroll
      for (int ks = 0; ks < 16; ++ks) {
        bf16x8 hb = __builtin_bit_cast(bf16x8, hfrag[ks]);
        acc0 = __builtin_amdgcn_mfma_f32_16x16x32_bf16(wfrag[ks], hb, acc0, 0, 0, 0);
        acc1 = __builtin_amdgcn_mfma_f32_16x16x32_bf16(wfrag[16 + ks], hb, acc1, 0, 0, 0);
      }

      // 4. gx(t): ACQUIRE-poll xflag[u], then 2 LDS reads (R10-proven)
      {
        const unsigned tgt = (unsigned)(t + 1);
        long g = 0;
        while (__hip_atomic_load(&xflag[u], __ATOMIC_ACQUIRE,
                                 __HIP_MEMORY_SCOPE_WORKGROUP) < tgt) {
          __builtin_amdgcn_s_sleep(1);
          if (++g > (1L << 20)) break;   // safety: corrupt visibly
        }
        asm volatile("" ::: "memory");
        __builtin_amdgcn_sched_barrier(0);
      }
      f32x4 g0 = acc0 + gx[t & 3][l15][8 * u + hi];
      f32x4 g1 = acc1 + gx[t & 3][l15][8 * u + 4 + hi];

      // 5. lane-local cell update (g*[r] = gate r: i,f,g,o)
      float iv0 = hsig(g0[0]), fv0 = hsig(g0[1]), ov0 = hsig(g0[3]);
      float gv0 = fast_tanh(g0[2]);
      cst0 = fv0 * cst0 + iv0 * gv0;
      float hv0 = ov0 * fast_tanh(cst0);
      float iv1 = hsig(g1[0]), fv1 = hsig(g1[1]), ov1 = hsig(g1[3]);
      float gv1 = fast_tanh(g1[2]);
      cst1 = fv1 * cst1 + iv1 * gv1;
      float hv1 = ov1 * fast_tanh(cst1);

      // 6. publish h_{t+1} (2 x 2B, HW-coalesced across hi lanes),
      //    own drain, own flag (R6-proven)
      {
        unsigned s0 = bf16bits(hv0), s1 = bf16bits(hv1);
        const __bf16* hq = hbuf + (size_t)((t + 1) & 1) * BATCH * HSZ + brow;
        const __bf16* hq0 = hq + j0;
        const __bf16* hq1 = hq + j1;
        STBF16(hq0, s0)
        STBF16(hq1, s1)
      }
      asm volatile("s_waitcnt vmcnt(0)" ::: "memory");
      if (lane == 0)
        __hip_atomic_store(&myf[wgi * 4 + u], (unsigned)(t + 2),
                           __ATOMIC_RELAXED, __HIP_MEMORY_SCOPE_AGENT);

      // 7. out stores AFTER the flag (drained by next step's publish drain)
      out[(size_t)t * BATCH * HSZ + brow + j0] = hv0;
      out[(size_t)t * BATCH * HSZ + brow + j1] = hv1;
      if (t == T_LEN - 1) {
        out[(size_t)T_LEN * BATCH * HSZ + brow + j0] = hv0;                       // hn
        out[(size_t)T_LEN * BATCH * HSZ + brow + j1] = hv1;
        out[(size_t)T_LEN * BATCH * HSZ + (size_t)BATCH * HSZ + brow + j0] = cst0; // cn
        out[(size_t)T_LEN * BATCH * HSZ + (size_t)BATCH * HSZ + brow + j1] = cst1;
      }
    }
  }
}

extern "C" void kernel_launch(void* const* d_in, const int* in_sizes, int n_in,
                              void* d_out, int out_size, void* d_ws, size_t ws_size,
                              hipStream_t stream) {
  const float* x    = (const float*)d_in[0];
  const float* h0   = (const float*)d_in[1];
  const float* c0   = (const float*)d_in[2];
  const float* w_ih = (const float*)d_in[3];
  const float* w_hh = (const float*)d_in[4];
  const float* b_ih = (const float*)d_in[5];
  const float* b_hh = (const float*)d_in[6];
  float* out = (float*)d_out;

  unsigned* flags = (unsigned*)d_ws;
  __bf16* hbuf    = (__bf16*)((char*)d_ws + 4096);
  // needs 4096 + 2*64*512*2 = ~132KB of workspace

  hipMemsetAsync(d_ws, 0, 4096, stream);  // zero flag words (ws is poisoned)

  hipLaunchKernelGGL(lstm_kernel, dim3(NWG), dim3(NTHR), 0, stream,
                     x, h0, c0, w_ih, w_hh, b_ih, b_hh, out, flags, hbuf);
}